// Round 2
// baseline (152.414 us; speedup 1.0000x reference)
//
#include <hip/hip_runtime.h>
#include <hip/hip_bf16.h>
#include <math.h>

// Problem constants (fixed by reference setup_inputs)
#define BN 8192       // batch
#define DK 256        // embedding dim (= GEMM K)
#define TM 128        // row/col tile
#define NP 41         // partial planes: 9 row-slots (dgroup) + 32 col-slots (d=1..32)
#define INV_T 1.42857142857142857f   // 1/0.7
#define C2E   2.060992915555662f     // log2(e)/0.7  (for exp2-based exp)

using bf16x8 = __attribute__((ext_vector_type(8))) short;  // 8 bf16 = 4 VGPRs
using f32x4  = __attribute__((ext_vector_type(4))) float;

__device__ __forceinline__ void async_copy16(void* lds, const void* g) {
  __builtin_amdgcn_global_load_lds(
      (const __attribute__((address_space(1))) unsigned int*)g,
      (__attribute__((address_space(3))) unsigned int*)lds,
      16, 0, 0);
}

// ---------------- Kernel 1: L2-normalize rows, fp32 -> bf16 ----------------
// One wave per row: float4 loads, shuffle reduce, ushort4 stores. No LDS.
// Also initializes the partial planes (plane-major [NP][BN]) and zeroes the
// 3-word accumulator (loss, count, ticket) so no hipMemset node is needed.
__global__ void norm_kernel(const float* __restrict__ E, unsigned short* __restrict__ Eb,
                            float* __restrict__ posPart, float* __restrict__ negPart,
                            float* __restrict__ accum) {
  const int gid = blockIdx.x * 256 + threadIdx.x;   // 2048*256 = 524288 threads
  if (gid < NP * BN) {                               // 335872 < 524288
    posPart[gid] = -1e30f;
    negPart[gid] = 0.0f;
  }
  if (blockIdx.x == 0 && threadIdx.x < 3) accum[threadIdx.x] = 0.0f;  // bits 0 == uint 0
  const int wv = threadIdx.x >> 6, lane = threadIdx.x & 63;
  const int row = blockIdx.x * 4 + wv;
  const float4 x = *(const float4*)&E[(size_t)row * DK + lane * 4];
  float ss = x.x * x.x + x.y * x.y + x.z * x.z + x.w * x.w;
#pragma unroll
  for (int m = 1; m < 64; m <<= 1) ss += __shfl_xor(ss, m);
  const float scale = 1.0f / fmaxf(sqrtf(ss), 1e-12f);
  ushort4 o;
  __hip_bfloat16 h0 = __float2bfloat16(x.x * scale); o.x = *(unsigned short*)&h0;
  __hip_bfloat16 h1 = __float2bfloat16(x.y * scale); o.y = *(unsigned short*)&h1;
  __hip_bfloat16 h2 = __float2bfloat16(x.z * scale); o.z = *(unsigned short*)&h2;
  __hip_bfloat16 h3 = __float2bfloat16(x.w * scale); o.w = *(unsigned short*)&h3;
  *(ushort4*)&Eb[(size_t)row * DK + lane * 4] = o;
}

// ---------------- Kernel 2: fused sims + masked max / sum-exp ----------------
// SYMMETRIC-HALVED tile set (each unordered 128x128 block-pair once):
// (I, (I+d)&63) for d=0..31 all I, plus d=32 for I<32 -> 2080 tiles.
// Block = (I, dgroup): dg<8 -> d=4dg..4dg+3; dg==8 (I<32, mapped to
// blockIdx.y==0 so they dispatch first) -> d=32.
//
// BARRIER-FREE INNER LOOP: A tile (128x256, 64 KB) persistent in LDS with a
// 16B-chunk XOR swizzle; B fragments are loaded GLOBAL->VGPR directly in the
// MFMA B-operand layout (Eb fits L2: 4 MB), double-buffered across kc.
// No B staging -> no per-kc barriers, no vmcnt(0) drains, half the LDS
// traffic. Only the off-diagonal column-stat reduce uses 2 barriers/tile.
// Partials: plane-major [NP][BN]; plane = dg (row stats) or 8+d (col stats).
__launch_bounds__(256, 2)
__global__ void contrast_kernel(const unsigned short* __restrict__ Eb,
                                const int* __restrict__ cat,
                                float* __restrict__ posPart,
                                float* __restrict__ negPart) {
  __shared__ __align__(16) unsigned short As[TM * DK];  // 64 KB, [row][k] swizzled
  __shared__ float sred[256];                           // 1 KB col-reduce scratch

  const int tid = threadIdx.x;
  const int lane = tid & 63;
  const int wv = tid >> 6;
  const int wm = wv >> 1;      // wave row (0..1)
  const int wn = wv & 1;       // wave col (0..1)
  const int quad = lane >> 4;
  const int l16 = lane & 15;
  const int sw = l16 & 7;      // per-lane swizzle key (row&7 == l16&7)

  const int I = blockIdx.x;
  const int dg = (blockIdx.y == 0) ? 8 : (int)blockIdx.y - 1;  // light blocks first
  if (dg == 8 && I >= 32) return;      // d=32 tiles exist only for I<32
  const int ntiles = (dg == 8) ? 1 : 4;
  const int rowBase = I * TM;

  // ---- stage A tile: 64 KB, swizzled source ----
  {
    const char* gbase = (const char*)(Eb + (size_t)rowBase * DK);
#pragma unroll
    for (int i = 0; i < 16; ++i) {
      const int chunk = tid + i * 256;   // LDS 16B-chunk index (lane-contiguous)
      const int row = chunk >> 5;        // 32 chunks per 512B row
      const int c = chunk & 31;
      async_copy16((char*)As + chunk * 16,
                   gbase + row * 512 + (c ^ (row & 7)) * 16);
    }
  }

  // Rows owned by this lane (C layout: col=lane&15, row=quad*4+reg):
  int catRow[16];
  float posmx[16], negsm[16];
#pragma unroll
  for (int ti = 0; ti < 4; ++ti)
#pragma unroll
    for (int r = 0; r < 4; ++r) {
      const int si = ti * 4 + r;
      catRow[si] = cat[rowBase + wm * 64 + ti * 16 + quad * 4 + r];
      posmx[si] = -1e30f;
      negsm[si] = 0.0f;
    }

  __syncthreads();  // As ready (barrier drains the global_load_lds queue)

// B fragment load: lane l16 = col (16 rows of 512B), quad = 16B k-chunk.
#define LOADB(buf, kcc)                                                       \
  {                                                                           \
    _Pragma("unroll") for (int s = 0; s < 2; ++s)                             \
      _Pragma("unroll") for (int tj = 0; tj < 4; ++tj)                        \
        buf[s][tj] = *(const bf16x8*)(bbase + (size_t)tj * 8192 +             \
                                      (kcc) * 128 + s * 64);                  \
  }
#define COMPUTE(buf, kcc)                                                     \
  {                                                                           \
    _Pragma("unroll") for (int s = 0; s < 2; ++s) {                           \
      bf16x8 a[4];                                                            \
      _Pragma("unroll") for (int ti = 0; ti < 4; ++ti)                        \
        a[ti] = *(const bf16x8*)&As[(wm * 64 + ti * 16 + l16) * DK +          \
                                    ((((kcc) * 8 + s * 4 + quad) ^ sw) << 3)];\
      _Pragma("unroll") for (int ti = 0; ti < 4; ++ti)                        \
        _Pragma("unroll") for (int tj = 0; tj < 4; ++tj)                      \
          acc[ti][tj] = __builtin_amdgcn_mfma_f32_16x16x32_bf16(              \
              a[ti], buf[s][tj], acc[ti][tj], 0, 0, 0);                       \
    }                                                                         \
  }

#pragma unroll 1
  for (int t = 0; t < ntiles; ++t) {
    const int d = (dg == 8) ? 32 : dg * 4 + t;   // block-distance of this tile
    const int J = (I + d) & 63;
    const int colBase = J * TM;
    const char* bbase = (const char*)Eb +
                        (size_t)(colBase + wn * 64 + l16) * 512 + quad * 16;

    f32x4 acc[4][4];
#pragma unroll
    for (int ti = 0; ti < 4; ++ti)
#pragma unroll
      for (int tj = 0; tj < 4; ++tj)
        acc[ti][tj] = f32x4{0.f, 0.f, 0.f, 0.f};

    bf16x8 bA[2][4], bB[2][4];   // kc ping-pong, 2-deep prefetch
    LOADB(bA, 0);
    LOADB(bB, 1);
    COMPUTE(bA, 0); LOADB(bA, 2);
    COMPUTE(bB, 1); LOADB(bB, 3);
    COMPUTE(bA, 2);
    COMPUTE(bB, 3);

    // ---- fused epilogue for this 128x128 tile (acc = raw cosines) ----
    int catCol[4];
#pragma unroll
    for (int tj = 0; tj < 4; ++tj) catCol[tj] = cat[colBase + wn * 64 + tj * 16 + l16];

    if (d == 0) {
      // diagonal tile: row stats only; self-exclusion needed; no col stats
#pragma unroll
      for (int ti = 0; ti < 4; ++ti)
#pragma unroll
        for (int r = 0; r < 4; ++r) {
          const int si = ti * 4 + r;
          const int rl = wm * 64 + ti * 16 + quad * 4 + r;   // local row
          float pm = posmx[si];
          float ns = negsm[si];
#pragma unroll
          for (int tj = 0; tj < 4; ++tj) {
            const float v = acc[ti][tj][r];
            const bool same = (catRow[si] == catCol[tj]);
            const bool self = (rl == wn * 64 + tj * 16 + l16);
            const float e = exp2f(__fmaf_rn(v, C2E, -C2E));
            ns += same ? 0.0f : e;
            pm = (same && !self) ? fmaxf(pm, v) : pm;
          }
          posmx[si] = pm;
          negsm[si] = ns;
        }
    } else {
      // off-diagonal: row stats + column stats (no self possible, I != J)
      float cp[4], cn[4];
#pragma unroll
      for (int tj = 0; tj < 4; ++tj) { cp[tj] = -1e30f; cn[tj] = 0.0f; }
#pragma unroll
      for (int ti = 0; ti < 4; ++ti)
#pragma unroll
        for (int r = 0; r < 4; ++r) {
          const int si = ti * 4 + r;
          float pm = posmx[si];
          float ns = negsm[si];
#pragma unroll
          for (int tj = 0; tj < 4; ++tj) {
            const float v = acc[ti][tj][r];
            const bool same = (catRow[si] == catCol[tj]);
            const float e = exp2f(__fmaf_rn(v, C2E, -C2E));
            const float en = same ? 0.0f : e;
            ns += en;
            cn[tj] += en;
            pm = same ? fmaxf(pm, v) : pm;
            cp[tj] = same ? fmaxf(cp[tj], v) : cp[tj];
          }
          posmx[si] = pm;
          negsm[si] = ns;
        }

      // column-stat reduce: quads via shuffle, wm halves via LDS scratch
#pragma unroll
      for (int tj = 0; tj < 4; ++tj) {
        cp[tj] = fmaxf(cp[tj], __shfl_xor(cp[tj], 16));
        cp[tj] = fmaxf(cp[tj], __shfl_xor(cp[tj], 32));
        cn[tj] += __shfl_xor(cn[tj], 16);
        cn[tj] += __shfl_xor(cn[tj], 32);
      }
      __syncthreads();           // prev tile's scratch reads done
      if (wm == 1 && quad == 0) {
#pragma unroll
        for (int tj = 0; tj < 4; ++tj) {
          sred[wn * 64 + tj * 16 + l16] = cp[tj];
          sred[128 + wn * 64 + tj * 16 + l16] = cn[tj];
        }
      }
      __syncthreads();           // scratch visible
      if (wm == 0 && quad == 0) {
#pragma unroll
        for (int tj = 0; tj < 4; ++tj) {
          const int C = colBase + wn * 64 + tj * 16 + l16;   // coalesced over l16
          posPart[(size_t)(8 + d) * BN + C] = fmaxf(cp[tj], sred[wn * 64 + tj * 16 + l16]);
          negPart[(size_t)(8 + d) * BN + C] = cn[tj] + sred[128 + wn * 64 + tj * 16 + l16];
        }
      }
    }
  }
#undef LOADB
#undef COMPUTE

  // ---- row stats: reduce across the 16 lanes sharing each row (cols split) ----
#pragma unroll
  for (int si = 0; si < 16; ++si) {
    float pm = posmx[si], ns = negsm[si];
#pragma unroll
    for (int m = 1; m < 16; m <<= 1) {
      pm = fmaxf(pm, __shfl_xor(pm, m));
      ns += __shfl_xor(ns, m);
    }
    posmx[si] = pm;
    negsm[si] = ns;
  }

  // ---- combine the wn=0 / wn=1 wave halves via LDS (reuse As) ----
  float* red = (float*)As;  // [0..127]=pos, [128..255]=neg
  __syncthreads();
  if (wn == 1 && l16 == 0) {
#pragma unroll
    for (int si = 0; si < 16; ++si) {
      const int rl = wm * 64 + (si >> 2) * 16 + quad * 4 + (si & 3);
      red[rl] = posmx[si];
      red[128 + rl] = negsm[si];
    }
  }
  __syncthreads();
  if (wn == 0 && l16 == 0) {
#pragma unroll
    for (int si = 0; si < 16; ++si) {
      const int rl = wm * 64 + (si >> 2) * 16 + quad * 4 + (si & 3);
      const float pm = fmaxf(posmx[si], red[rl]);
      const float ns = negsm[si] + red[128 + rl];
      posPart[(size_t)dg * BN + rowBase + rl] = pm;  // raw cosine max
      negPart[(size_t)dg * BN + rowBase + rl] = ns;
    }
  }
}

// ---------------- Kernel 3: per-row loss, accumulate, final division ----------------
// 32 blocks x 256: one thread per row; plane-major partials -> each of the NP
// reads is a fully-coalesced 256-thread load. Last block (atomic ticket)
// performs the division -- no separate epilogue kernel, no memset node.
__global__ void finalize_kernel(const float* __restrict__ posPart,
                                const float* __restrict__ negPart,
                                float* __restrict__ accum,
                                float* __restrict__ out) {
  const int tid = threadIdx.x;
  const int row = blockIdx.x * 256 + tid;
  float pm = -1e30f, ns = 0.0f;
#pragma unroll
  for (int g = 0; g < NP; ++g) {
    pm = fmaxf(pm, posPart[(size_t)g * BN + row]);
    ns += negPart[(size_t)g * BN + row];
  }
  float loss = 0.0f, c = 0.0f;
  if (pm > -1e29f && ns > 0.0f) {   // valid: has positive AND negative
    const float pos = pm * INV_T;
    const float lse = INV_T + logf(expf(pos - INV_T) + ns);
    loss = lse - pos;
    c = 1.0f;
  }
#pragma unroll
  for (int m = 1; m < 64; m <<= 1) {
    loss += __shfl_xor(loss, m);
    c += __shfl_xor(c, m);
  }
  __shared__ float sL[4], sC[4];
  const int wv = tid >> 6, lane = tid & 63;
  if (lane == 0) { sL[wv] = loss; sC[wv] = c; }
  __syncthreads();
  if (tid == 0) {
    atomicAdd(&accum[0], sL[0] + sL[1] + sL[2] + sL[3]);
    atomicAdd(&accum[1], sC[0] + sC[1] + sC[2] + sC[3]);
    __threadfence();
    const unsigned old = atomicAdd((unsigned*)&accum[2], 1u);
    if (old == 31u) {            // last block: totals are visible (fence+ticket)
      const float L = atomicAdd(&accum[0], 0.0f);
      const float C = atomicAdd(&accum[1], 0.0f);
      out[0] = (C > 0.0f) ? L / C : 0.0f;
    }
  }
}

extern "C" void kernel_launch(void* const* d_in, const int* in_sizes, int n_in,
                              void* d_out, int out_size, void* d_ws, size_t ws_size,
                              hipStream_t stream) {
  const float* E = (const float*)d_in[0];
  const int* cat = (const int*)d_in[1];
  // d_in[2] (font_labels) unused by the reference.

  // Workspace: [0,4MB) bf16 normalized embeddings; [NP][BN] partials x2; 12B accum.
  unsigned short* Eb = (unsigned short*)d_ws;
  float* posPart = (float*)((char*)d_ws + (size_t)BN * DK * 2);
  float* negPart = posPart + (size_t)NP * BN;
  float* accum = negPart + (size_t)NP * BN;
  float* out = (float*)d_out;

  hipLaunchKernelGGL(norm_kernel, dim3(BN / 4), dim3(256), 0, stream,
                     E, Eb, posPart, negPart, accum);
  hipLaunchKernelGGL(contrast_kernel, dim3(BN / TM, 9), dim3(256), 0, stream,
                     Eb, cat, posPart, negPart);
  hipLaunchKernelGGL(finalize_kernel, dim3(BN / 256), dim3(256), 0, stream,
                     posPart, negPart, accum, out);
}

// Round 3
// 147.321 us; speedup vs baseline: 1.0346x; 1.0346x over previous
//
#include <hip/hip_runtime.h>
#include <hip/hip_bf16.h>
#include <math.h>

// Problem constants (fixed by reference setup_inputs)
#define BN 8192       // batch
#define DK 256        // embedding dim (= GEMM K)
#define TM 128        // row/col tile
#define BK 32         // K chunk per pipeline stage
#define NP 41         // partial planes: 9 row-slots (dgroup) + 32 col-slots (d=1..32)
#define INV_T 1.42857142857142857f   // 1/0.7
#define C2E   2.060992915555662f     // log2(e)/0.7  (for exp2-based exp)

using bf16x8 = __attribute__((ext_vector_type(8))) short;  // 8 bf16 = 4 VGPRs
using f32x4  = __attribute__((ext_vector_type(4))) float;

__device__ __forceinline__ void async_copy16(void* lds, const void* g) {
  __builtin_amdgcn_global_load_lds(
      (const __attribute__((address_space(1))) unsigned int*)g,
      (__attribute__((address_space(3))) unsigned int*)lds,
      16, 0, 0);
}

// ---------------- Kernel 1: L2-normalize rows, fp32 -> bf16 ----------------
// One wave per row: float4 loads, shuffle reduce, ushort4 stores. No LDS.
// Also initializes the partial planes (plane-major [NP][BN]) and zeroes the
// 3-word accumulator (loss, count, ticket) so no hipMemset node is needed.
__global__ void norm_kernel(const float* __restrict__ E, unsigned short* __restrict__ Eb,
                            float* __restrict__ posPart, float* __restrict__ negPart,
                            float* __restrict__ accum) {
  const int gid = blockIdx.x * 256 + threadIdx.x;   // 2048*256 = 524288 threads
  if (gid < NP * BN) {                               // 335872 < 524288
    posPart[gid] = -1e30f;
    negPart[gid] = 0.0f;
  }
  if (blockIdx.x == 0 && threadIdx.x < 3) accum[threadIdx.x] = 0.0f;  // bits 0 == uint 0
  const int wv = threadIdx.x >> 6, lane = threadIdx.x & 63;
  const int row = blockIdx.x * 4 + wv;
  const float4 x = *(const float4*)&E[(size_t)row * DK + lane * 4];
  float ss = x.x * x.x + x.y * x.y + x.z * x.z + x.w * x.w;
#pragma unroll
  for (int m = 1; m < 64; m <<= 1) ss += __shfl_xor(ss, m);
  const float scale = 1.0f / fmaxf(sqrtf(ss), 1e-12f);
  ushort4 o;
  __hip_bfloat16 h0 = __float2bfloat16(x.x * scale); o.x = *(unsigned short*)&h0;
  __hip_bfloat16 h1 = __float2bfloat16(x.y * scale); o.y = *(unsigned short*)&h1;
  __hip_bfloat16 h2 = __float2bfloat16(x.z * scale); o.z = *(unsigned short*)&h2;
  __hip_bfloat16 h3 = __float2bfloat16(x.w * scale); o.w = *(unsigned short*)&h3;
  *(ushort4*)&Eb[(size_t)row * DK + lane * 4] = o;
}

// ---------------- Kernel 2: fused sims + masked max / sum-exp ----------------
// SYMMETRIC-HALVED tile set (each unordered 128x128 block-pair once):
// (I, (I+d)&63) for d=0..31 all I, plus d=32 for I<32 -> 2080 tiles.
// Block = (I, dgroup): dg<8 -> d=4dg..4dg+3; dg==8 (I<32, mapped to
// blockIdx.y==0 so they dispatch first) -> d=32.
//
// PIPELINED LOOP (T3 2-phase): Bs is a BK=32 ping-pong pair; each kc issues
// the NEXT chunk's global_load_lds BEFORE computing the current one, so the
// barrier's vmcnt(0) drain costs ~nothing. kc=7 prefetches the next tile's
// first chunk -> the pipe never empties inside a block.
// CONFLICT-FREE LDS: As and Bs are stored as [panel][kq][c16] 16B chunks so
// each ds_read_b128 reads 1024 CONTIGUOUS bytes (zero bank conflicts by
// construction); staging keeps full 64B-sector efficiency (4 thr/line).
// LDS = 64 KB As + 2x8 KB Bs = 80 KB exactly -> 2 blocks/CU.
// Partials: plane-major [NP][BN]; plane = dg (row stats) or 8+d (col stats).
__launch_bounds__(256, 2)
__global__ void contrast_kernel(const unsigned short* __restrict__ Eb,
                                const int* __restrict__ cat,
                                float* __restrict__ posPart,
                                float* __restrict__ negPart) {
  // As chunk layout: idx = (rh*8 + kc)*64 + q*16 + c16
  //   holds global A[row = rh*16 + c16][k = kc*32 + q*8 .. +8]
  __shared__ __align__(16) unsigned short As[TM * DK];       // 64 KB
  // Bs[buf] chunk layout: idx = colhi*64 + q*16 + c16
  //   holds global B[col = colhi*16 + c16][k = kc*32 + q*8 .. +8]
  __shared__ __align__(16) unsigned short Bs[2][TM * BK];    // 2 x 8 KB

  const int tid = threadIdx.x;
  const int lane = tid & 63;
  const int wv = tid >> 6;
  const int wm = wv >> 1;      // wave row (0..1)
  const int wn = wv & 1;       // wave col (0..1)
  const int quad = lane >> 4;
  const int l16 = lane & 15;

  const int I = blockIdx.x;
  const int dg = (blockIdx.y == 0) ? 8 : (int)blockIdx.y - 1;  // light blocks first
  if (dg == 8 && I >= 32) return;      // d=32 tiles exist only for I<32
  const int ntiles = (dg == 8) ? 1 : 4;
  const int rowBase = I * TM;
  const int d0 = (dg == 8) ? 32 : dg * 4;

// Stage one BK=32 B chunk (8 KB, 2 copies/thread) for columns [cb, cb+128).
#define STAGEB(bufidx, cb, kcs)                                               \
  {                                                                           \
    _Pragma("unroll") for (int r2 = 0; r2 < 2; ++r2) {                        \
      const int idx = tid + r2 * 256;                                         \
      const int colhi = idx >> 6, q = (idx >> 4) & 3, c16 = idx & 15;         \
      async_copy16((char*)Bs[bufidx] + idx * 16,                              \
                   (const char*)Eb + (size_t)((cb) + colhi * 16 + c16) * 512  \
                       + (kcs) * 64 + q * 16);                                \
    }                                                                         \
  }

// One K=32 step: 4 A frags + 4 B frags (contiguous 1024B ds_read_b128 each),
// 16 MFMA with raised priority.
#define COMPUTE(bufidx, kcc)                                                  \
  {                                                                           \
    bf16x8 a[4], b[4];                                                        \
    _Pragma("unroll") for (int ti = 0; ti < 4; ++ti)                          \
      a[ti] = *(const bf16x8*)((const char*)As +                              \
              ((((wm * 4 + ti) * 8 + (kcc)) * 64 + quad * 16 + l16) * 16));   \
    _Pragma("unroll") for (int tj = 0; tj < 4; ++tj)                          \
      b[tj] = *(const bf16x8*)((const char*)Bs[bufidx] +                      \
              (((wn * 4 + tj) * 64 + quad * 16 + l16) * 16));                 \
    __builtin_amdgcn_s_setprio(1);                                            \
    _Pragma("unroll") for (int ti = 0; ti < 4; ++ti)                          \
      _Pragma("unroll") for (int tj = 0; tj < 4; ++tj)                        \
        acc[ti][tj] = __builtin_amdgcn_mfma_f32_16x16x32_bf16(                \
            a[ti], b[tj], acc[ti][tj], 0, 0, 0);                              \
    __builtin_amdgcn_s_setprio(0);                                            \
  }

  // ---- prologue: stage full A panel + first B chunk ----
  {
    const char* gbase = (const char*)(Eb + (size_t)rowBase * DK);
#pragma unroll
    for (int i = 0; i < 16; ++i) {
      const int idx = tid + i * 256;       // 4096 chunks of 16B
      const int rhkc = idx >> 6;           // rh = rhkc>>3, kc = rhkc&7
      const int q = (idx >> 4) & 3, c16 = idx & 15;
      async_copy16((char*)As + idx * 16,
                   gbase + ((rhkc >> 3) * 16 + c16) * 512 +
                       ((rhkc & 7) * 4 + q) * 16);
    }
  }
  {
    const int cb0 = ((I + d0) & 63) * TM;
    STAGEB(0, cb0, 0);
  }

  // Rows owned by this lane (C layout: col=lane&15, row=quad*4+reg):
  int catRow[16];
  float posmx[16], negsm[16];
#pragma unroll
  for (int ti = 0; ti < 4; ++ti)
#pragma unroll
    for (int r = 0; r < 4; ++r) {
      const int si = ti * 4 + r;
      catRow[si] = cat[rowBase + wm * 64 + ti * 16 + quad * 4 + r];
      posmx[si] = -1e30f;
      negsm[si] = 0.0f;
    }

  __syncthreads();  // A panel + B chunk 0 ready (drains global_load_lds queue)

#pragma unroll 1
  for (int t = 0; t < ntiles; ++t) {
    const int d = (dg == 8) ? 32 : dg * 4 + t;   // block-distance of this tile
    const int colBase = ((I + d) & 63) * TM;
    const bool hasNext = (t + 1 < ntiles);
    const int colBaseNext = hasNext ? ((I + d + 1) & 63) * TM : 0;

    f32x4 acc[4][4];
#pragma unroll
    for (int ti = 0; ti < 4; ++ti)
#pragma unroll
      for (int tj = 0; tj < 4; ++tj)
        acc[ti][tj] = f32x4{0.f, 0.f, 0.f, 0.f};

    // 2-phase pipeline: stage(kc+1) || compute(kc); one barrier per kc.
#pragma unroll
    for (int kc = 0; kc < 8; ++kc) {
      if (kc < 7) {
        STAGEB((kc + 1) & 1, colBase, kc + 1);
      } else if (hasNext) {
        STAGEB(0, colBaseNext, 0);   // (kc+1)&1 == 0: parity stays continuous
      }
      COMPUTE(kc & 1, kc);
      __syncthreads();   // stage landed (had a full kc of compute to hide)
    }
    // After kc=7's barrier: buf1 reads done; buf0 holds next tile's chunk 0.
    // buf1 is dead until next tile's kc=0 issues stage(kc=1 -> buf1).

    // ---- fused epilogue for this 128x128 tile (acc = raw cosines) ----
    int catCol[4];
#pragma unroll
    for (int tj = 0; tj < 4; ++tj) catCol[tj] = cat[colBase + wn * 64 + tj * 16 + l16];

    if (d == 0) {
      // diagonal tile: row stats only; self-exclusion needed; no col stats
#pragma unroll
      for (int ti = 0; ti < 4; ++ti)
#pragma unroll
        for (int r = 0; r < 4; ++r) {
          const int si = ti * 4 + r;
          const int rl = wm * 64 + ti * 16 + quad * 4 + r;   // local row
          float pm = posmx[si];
          float ns = negsm[si];
#pragma unroll
          for (int tj = 0; tj < 4; ++tj) {
            const float v = acc[ti][tj][r];
            const bool same = (catRow[si] == catCol[tj]);
            const bool self = (rl == wn * 64 + tj * 16 + l16);
            const float e = exp2f(__fmaf_rn(v, C2E, -C2E));
            ns += same ? 0.0f : e;
            pm = (same && !self) ? fmaxf(pm, v) : pm;
          }
          posmx[si] = pm;
          negsm[si] = ns;
        }
    } else {
      // off-diagonal: row stats + column stats (no self possible, I != J)
      float cp[4], cn[4];
#pragma unroll
      for (int tj = 0; tj < 4; ++tj) { cp[tj] = -1e30f; cn[tj] = 0.0f; }
#pragma unroll
      for (int ti = 0; ti < 4; ++ti)
#pragma unroll
        for (int r = 0; r < 4; ++r) {
          const int si = ti * 4 + r;
          float pm = posmx[si];
          float ns = negsm[si];
#pragma unroll
          for (int tj = 0; tj < 4; ++tj) {
            const float v = acc[ti][tj][r];
            const bool same = (catRow[si] == catCol[tj]);
            const float e = exp2f(__fmaf_rn(v, C2E, -C2E));
            const float en = same ? 0.0f : e;
            ns += en;
            cn[tj] += en;
            pm = same ? fmaxf(pm, v) : pm;
            cp[tj] = same ? fmaxf(cp[tj], v) : cp[tj];
          }
          posmx[si] = pm;
          negsm[si] = ns;
        }

      // column-stat reduce: quads via shuffle, wm halves via idle buf1 scratch
#pragma unroll
      for (int tj = 0; tj < 4; ++tj) {
        cp[tj] = fmaxf(cp[tj], __shfl_xor(cp[tj], 16));
        cp[tj] = fmaxf(cp[tj], __shfl_xor(cp[tj], 32));
        cn[tj] += __shfl_xor(cn[tj], 16);
        cn[tj] += __shfl_xor(cn[tj], 32);
      }
      float* sred = (float*)&Bs[1][0];   // buf1: dead between kc=7 and next kc=0 stage
      if (wm == 1 && quad == 0) {
#pragma unroll
        for (int tj = 0; tj < 4; ++tj) {
          sred[wn * 64 + tj * 16 + l16] = cp[tj];
          sred[128 + wn * 64 + tj * 16 + l16] = cn[tj];
        }
      }
      __syncthreads();           // scratch visible
      if (wm == 0 && quad == 0) {
#pragma unroll
        for (int tj = 0; tj < 4; ++tj) {
          const int C = colBase + wn * 64 + tj * 16 + l16;   // coalesced over l16
          posPart[(size_t)(8 + d) * BN + C] = fmaxf(cp[tj], sred[wn * 64 + tj * 16 + l16]);
          negPart[(size_t)(8 + d) * BN + C] = cn[tj] + sred[128 + wn * 64 + tj * 16 + l16];
        }
      }
      __syncthreads();           // sred reads done before next tile stages buf1
    }
  }
#undef STAGEB
#undef COMPUTE

  // ---- row stats: reduce across the 16 lanes sharing each row (cols split) ----
#pragma unroll
  for (int si = 0; si < 16; ++si) {
    float pm = posmx[si], ns = negsm[si];
#pragma unroll
    for (int m = 1; m < 16; m <<= 1) {
      pm = fmaxf(pm, __shfl_xor(pm, m));
      ns += __shfl_xor(ns, m);
    }
    posmx[si] = pm;
    negsm[si] = ns;
  }

  // ---- combine the wn=0 / wn=1 wave halves via LDS (reuse As) ----
  float* red = (float*)As;  // [0..127]=pos, [128..255]=neg
  __syncthreads();
  if (wn == 1 && l16 == 0) {
#pragma unroll
    for (int si = 0; si < 16; ++si) {
      const int rl = wm * 64 + (si >> 2) * 16 + quad * 4 + (si & 3);
      red[rl] = posmx[si];
      red[128 + rl] = negsm[si];
    }
  }
  __syncthreads();
  if (wn == 0 && l16 == 0) {
#pragma unroll
    for (int si = 0; si < 16; ++si) {
      const int rl = wm * 64 + (si >> 2) * 16 + quad * 4 + (si & 3);
      const float pm = fmaxf(posmx[si], red[rl]);
      const float ns = negsm[si] + red[128 + rl];
      posPart[(size_t)dg * BN + rowBase + rl] = pm;  // raw cosine max
      negPart[(size_t)dg * BN + rowBase + rl] = ns;
    }
  }
}

// ---------------- Kernel 3: per-row loss, accumulate, final division ----------------
// 32 blocks x 256: one thread per row; plane-major partials -> each of the NP
// reads is a fully-coalesced 256-thread load. Last block (atomic ticket)
// performs the division -- no separate epilogue kernel, no memset node.
__global__ void finalize_kernel(const float* __restrict__ posPart,
                                const float* __restrict__ negPart,
                                float* __restrict__ accum,
                                float* __restrict__ out) {
  const int tid = threadIdx.x;
  const int row = blockIdx.x * 256 + tid;
  float pm = -1e30f, ns = 0.0f;
#pragma unroll
  for (int g = 0; g < NP; ++g) {
    pm = fmaxf(pm, posPart[(size_t)g * BN + row]);
    ns += negPart[(size_t)g * BN + row];
  }
  float loss = 0.0f, c = 0.0f;
  if (pm > -1e29f && ns > 0.0f) {   // valid: has positive AND negative
    const float pos = pm * INV_T;
    const float lse = INV_T + logf(expf(pos - INV_T) + ns);
    loss = lse - pos;
    c = 1.0f;
  }
#pragma unroll
  for (int m = 1; m < 64; m <<= 1) {
    loss += __shfl_xor(loss, m);
    c += __shfl_xor(c, m);
  }
  __shared__ float sL[4], sC[4];
  const int wv = tid >> 6, lane = tid & 63;
  if (lane == 0) { sL[wv] = loss; sC[wv] = c; }
  __syncthreads();
  if (tid == 0) {
    atomicAdd(&accum[0], sL[0] + sL[1] + sL[2] + sL[3]);
    atomicAdd(&accum[1], sC[0] + sC[1] + sC[2] + sC[3]);
    __threadfence();
    const unsigned old = atomicAdd((unsigned*)&accum[2], 1u);
    if (old == 31u) {            // last block: totals are visible (fence+ticket)
      const float L = atomicAdd(&accum[0], 0.0f);
      const float C = atomicAdd(&accum[1], 0.0f);
      out[0] = (C > 0.0f) ? L / C : 0.0f;
    }
  }
}

extern "C" void kernel_launch(void* const* d_in, const int* in_sizes, int n_in,
                              void* d_out, int out_size, void* d_ws, size_t ws_size,
                              hipStream_t stream) {
  const float* E = (const float*)d_in[0];
  const int* cat = (const int*)d_in[1];
  // d_in[2] (font_labels) unused by the reference.

  // Workspace: [0,4MB) bf16 normalized embeddings; [NP][BN] partials x2; 12B accum.
  unsigned short* Eb = (unsigned short*)d_ws;
  float* posPart = (float*)((char*)d_ws + (size_t)BN * DK * 2);
  float* negPart = posPart + (size_t)NP * BN;
  float* accum = negPart + (size_t)NP * BN;
  float* out = (float*)d_out;

  hipLaunchKernelGGL(norm_kernel, dim3(BN / 4), dim3(256), 0, stream,
                     E, Eb, posPart, negPart, accum);
  hipLaunchKernelGGL(contrast_kernel, dim3(BN / TM, 9), dim3(256), 0, stream,
                     Eb, cat, posPart, negPart);
  hipLaunchKernelGGL(finalize_kernel, dim3(BN / 256), dim3(256), 0, stream,
                     posPart, negPart, accum, out);
}

// Round 4
// 145.908 us; speedup vs baseline: 1.0446x; 1.0097x over previous
//
#include <hip/hip_runtime.h>
#include <hip/hip_bf16.h>
#include <math.h>

// Problem constants (fixed by reference setup_inputs)
#define BN 8192       // batch
#define DK 256        // embedding dim (= GEMM K)
#define TM 128        // row/col tile
#define BK 32         // K chunk per pipeline stage
#define NP 41         // partial planes: 9 row-slots (dgroup) + 32 col-slots (d=1..32)
#define INV_T 1.42857142857142857f   // 1/0.7
#define C2E   2.060992915555662f     // log2(e)/0.7  (for exp2-based exp)

using bf16x8 = __attribute__((ext_vector_type(8))) short;  // 8 bf16 = 4 VGPRs
using f32x4  = __attribute__((ext_vector_type(4))) float;

__device__ __forceinline__ void async_copy16(void* lds, const void* g) {
  __builtin_amdgcn_global_load_lds(
      (const __attribute__((address_space(1))) unsigned int*)g,
      (__attribute__((address_space(3))) unsigned int*)lds,
      16, 0, 0);
}

// ---------------- Kernel 1: L2-normalize rows, fp32 -> bf16 ----------------
// One wave per row: float4 loads, shuffle reduce, ushort4 stores. No LDS.
// Also initializes the partial planes (plane-major [NP][BN]) and zeroes the
// 3-word accumulator (loss, count, ticket) so no hipMemset node is needed.
__global__ void norm_kernel(const float* __restrict__ E, unsigned short* __restrict__ Eb,
                            float* __restrict__ posPart, float* __restrict__ negPart,
                            float* __restrict__ accum) {
  const int gid = blockIdx.x * 256 + threadIdx.x;   // 2048*256 = 524288 threads
  if (gid < NP * BN) {                               // 335872 < 524288
    posPart[gid] = -1e30f;
    negPart[gid] = 0.0f;
  }
  if (blockIdx.x == 0 && threadIdx.x < 3) accum[threadIdx.x] = 0.0f;  // bits 0 == uint 0
  const int wv = threadIdx.x >> 6, lane = threadIdx.x & 63;
  const int row = blockIdx.x * 4 + wv;
  const float4 x = *(const float4*)&E[(size_t)row * DK + lane * 4];
  float ss = x.x * x.x + x.y * x.y + x.z * x.z + x.w * x.w;
#pragma unroll
  for (int m = 1; m < 64; m <<= 1) ss += __shfl_xor(ss, m);
  const float scale = 1.0f / fmaxf(sqrtf(ss), 1e-12f);
  ushort4 o;
  __hip_bfloat16 h0 = __float2bfloat16(x.x * scale); o.x = *(unsigned short*)&h0;
  __hip_bfloat16 h1 = __float2bfloat16(x.y * scale); o.y = *(unsigned short*)&h1;
  __hip_bfloat16 h2 = __float2bfloat16(x.z * scale); o.z = *(unsigned short*)&h2;
  __hip_bfloat16 h3 = __float2bfloat16(x.w * scale); o.w = *(unsigned short*)&h3;
  *(ushort4*)&Eb[(size_t)row * DK + lane * 4] = o;
}

// ---------------- Kernel 2: fused sims + masked max / sum-exp ----------------
// SYMMETRIC-HALVED tile set (each unordered 128x128 block-pair once):
// (I, (I+d)&63) for d=0..31 all I, plus d=32 for I<32 -> 2080 tiles.
// Block = (I, dgroup): dg<8 -> d=4dg..4dg+3; dg==8 (I<32, mapped to
// blockIdx.y==0 so they dispatch first) -> d=32.
//
// PIPELINED LOOP: Bs is a BK=32 ping-pong pair; each phase issues the NEXT
// chunk's global_load_lds BEFORE computing the current one, so the barrier's
// vmcnt(0) drain overlaps ~a full compute phase. The kc loop is
// `#pragma unroll 1` x4 with TWO STATIC PHASES inside (buf0 then buf1):
// round-3's full unroll made the scheduler hoist 8 iterations of frag loads
// and spill (WRITE_SIZE 2.5->43 MB); this shape is the round-1-proven
// spill-free one. Buffer indices are compile-time constants.
// CONFLICT-FREE LDS: As and Bs stored as [panel][kq][c16] 16B chunks so each
// ds_read_b128 reads 1024 CONTIGUOUS bytes (zero bank conflicts, verified
// r3: SQ_LDS_BANK_CONFLICT = 0); staging keeps 64B-sector efficiency.
// LDS = 64 KB As + 2x8 KB Bs = 80 KB -> 2 blocks/CU.
// Partials: plane-major [NP][BN]; plane = dg (row stats) or 8+d (col stats).
__launch_bounds__(256, 2)
__global__ void contrast_kernel(const unsigned short* __restrict__ Eb,
                                const int* __restrict__ cat,
                                float* __restrict__ posPart,
                                float* __restrict__ negPart) {
  // As chunk layout: idx = (rh*8 + kc)*64 + q*16 + c16
  //   holds global A[row = rh*16 + c16][k = kc*32 + q*8 .. +8]
  __shared__ __align__(16) unsigned short As[TM * DK];       // 64 KB
  // Bs[buf] chunk layout: idx = colhi*64 + q*16 + c16
  //   holds global B[col = colhi*16 + c16][k = kc*32 + q*8 .. +8]
  __shared__ __align__(16) unsigned short Bs[2][TM * BK];    // 2 x 8 KB

  const int tid = threadIdx.x;
  const int lane = tid & 63;
  const int wv = tid >> 6;
  const int wm = wv >> 1;      // wave row (0..1)
  const int wn = wv & 1;       // wave col (0..1)
  const int quad = lane >> 4;
  const int l16 = lane & 15;

  const int I = blockIdx.x;
  const int dg = (blockIdx.y == 0) ? 8 : (int)blockIdx.y - 1;  // light blocks first
  if (dg == 8 && I >= 32) return;      // d=32 tiles exist only for I<32
  const int ntiles = (dg == 8) ? 1 : 4;
  const int rowBase = I * TM;
  const int d0 = (dg == 8) ? 32 : dg * 4;

// Stage one BK=32 B chunk (8 KB, 2 copies/thread) for columns [cb, cb+128).
#define STAGEB(bufidx, cb, kcs)                                               \
  {                                                                           \
    _Pragma("unroll") for (int r2 = 0; r2 < 2; ++r2) {                        \
      const int idx = tid + r2 * 256;                                         \
      const int colhi = idx >> 6, q = (idx >> 4) & 3, c16 = idx & 15;         \
      async_copy16((char*)Bs[bufidx] + idx * 16,                              \
                   (const char*)Eb + (size_t)((cb) + colhi * 16 + c16) * 512  \
                       + (kcs) * 64 + q * 16);                                \
    }                                                                         \
  }

// One K=32 step: 4 A frags + 4 B frags (contiguous 1024B ds_read_b128 each),
// 16 MFMA with raised priority.
#define COMPUTE(bufidx, kcc)                                                  \
  {                                                                           \
    bf16x8 a[4], b[4];                                                        \
    _Pragma("unroll") for (int ti = 0; ti < 4; ++ti)                          \
      a[ti] = *(const bf16x8*)((const char*)As +                              \
              ((((wm * 4 + ti) * 8 + (kcc)) * 64 + quad * 16 + l16) * 16));   \
    _Pragma("unroll") for (int tj = 0; tj < 4; ++tj)                          \
      b[tj] = *(const bf16x8*)((const char*)Bs[bufidx] +                      \
              (((wn * 4 + tj) * 64 + quad * 16 + l16) * 16));                 \
    __builtin_amdgcn_s_setprio(1);                                            \
    _Pragma("unroll") for (int ti = 0; ti < 4; ++ti)                          \
      _Pragma("unroll") for (int tj = 0; tj < 4; ++tj)                        \
        acc[ti][tj] = __builtin_amdgcn_mfma_f32_16x16x32_bf16(                \
            a[ti], b[tj], acc[ti][tj], 0, 0, 0);                              \
    __builtin_amdgcn_s_setprio(0);                                            \
  }

  // ---- prologue: stage full A panel + first B chunk ----
  {
    const char* gbase = (const char*)(Eb + (size_t)rowBase * DK);
#pragma unroll
    for (int i = 0; i < 16; ++i) {
      const int idx = tid + i * 256;       // 4096 chunks of 16B
      const int rhkc = idx >> 6;           // rh = rhkc>>3, kc = rhkc&7
      const int q = (idx >> 4) & 3, c16 = idx & 15;
      async_copy16((char*)As + idx * 16,
                   gbase + ((rhkc >> 3) * 16 + c16) * 512 +
                       ((rhkc & 7) * 4 + q) * 16);
    }
  }
  {
    const int cb0 = ((I + d0) & 63) * TM;
    STAGEB(0, cb0, 0);
  }

  // Rows owned by this lane (C layout: col=lane&15, row=quad*4+reg):
  int catRow[16];
  float posmx[16], negsm[16];
#pragma unroll
  for (int ti = 0; ti < 4; ++ti)
#pragma unroll
    for (int r = 0; r < 4; ++r) {
      const int si = ti * 4 + r;
      catRow[si] = cat[rowBase + wm * 64 + ti * 16 + quad * 4 + r];
      posmx[si] = -1e30f;
      negsm[si] = 0.0f;
    }

  __syncthreads();  // A panel + B chunk 0 ready (drains global_load_lds queue)

#pragma unroll 1
  for (int t = 0; t < ntiles; ++t) {
    const int d = (dg == 8) ? 32 : dg * 4 + t;   // block-distance of this tile
    const int colBase = ((I + d) & 63) * TM;
    const bool hasNext = (t + 1 < ntiles);
    const int colBaseNext = hasNext ? ((I + d + 1) & 63) * TM : 0;

    f32x4 acc[4][4];
#pragma unroll
    for (int ti = 0; ti < 4; ++ti)
#pragma unroll
      for (int tj = 0; tj < 4; ++tj)
        acc[ti][tj] = f32x4{0.f, 0.f, 0.f, 0.f};

    // 2-phase pipeline, unroll-1 outer loop, static buffer parity inside:
    //   phase A: stage chunk 2k+1 -> buf1, compute chunk 2k from buf0
    //   phase B: stage chunk 2k+2 -> buf0 (or next tile's chunk 0),
    //            compute chunk 2k+1 from buf1
#pragma unroll 1
    for (int kc2 = 0; kc2 < 4; ++kc2) {
      STAGEB(1, colBase, 2 * kc2 + 1);
      COMPUTE(0, 2 * kc2);
      __syncthreads();   // buf1 landed (hidden under compute)
      if (kc2 < 3) {
        STAGEB(0, colBase, 2 * kc2 + 2);
      } else if (hasNext) {
        STAGEB(0, colBaseNext, 0);   // cross-tile prefetch, parity continuous
      }
      COMPUTE(1, 2 * kc2 + 1);
      __syncthreads();   // buf0 landed
    }
    // After the last barrier: buf0 holds next tile's chunk 0; buf1 is dead
    // until next tile's phase A stage -> usable as epilogue scratch.

    // ---- fused epilogue for this 128x128 tile (acc = raw cosines) ----
    int catCol[4];
#pragma unroll
    for (int tj = 0; tj < 4; ++tj) catCol[tj] = cat[colBase + wn * 64 + tj * 16 + l16];

    if (d == 0) {
      // diagonal tile: row stats only; self-exclusion needed; no col stats
#pragma unroll
      for (int ti = 0; ti < 4; ++ti)
#pragma unroll
        for (int r = 0; r < 4; ++r) {
          const int si = ti * 4 + r;
          const int rl = wm * 64 + ti * 16 + quad * 4 + r;   // local row
          float pm = posmx[si];
          float ns = negsm[si];
#pragma unroll
          for (int tj = 0; tj < 4; ++tj) {
            const float v = acc[ti][tj][r];
            const bool same = (catRow[si] == catCol[tj]);
            const bool self = (rl == wn * 64 + tj * 16 + l16);
            const float e = exp2f(__fmaf_rn(v, C2E, -C2E));
            ns += same ? 0.0f : e;
            pm = (same && !self) ? fmaxf(pm, v) : pm;
          }
          posmx[si] = pm;
          negsm[si] = ns;
        }
    } else {
      // off-diagonal: row stats + column stats (no self possible, I != J)
      float cp[4], cn[4];
#pragma unroll
      for (int tj = 0; tj < 4; ++tj) { cp[tj] = -1e30f; cn[tj] = 0.0f; }
#pragma unroll
      for (int ti = 0; ti < 4; ++ti)
#pragma unroll
        for (int r = 0; r < 4; ++r) {
          const int si = ti * 4 + r;
          float pm = posmx[si];
          float ns = negsm[si];
#pragma unroll
          for (int tj = 0; tj < 4; ++tj) {
            const float v = acc[ti][tj][r];
            const bool same = (catRow[si] == catCol[tj]);
            const float e = exp2f(__fmaf_rn(v, C2E, -C2E));
            const float en = same ? 0.0f : e;
            ns += en;
            cn[tj] += en;
            pm = same ? fmaxf(pm, v) : pm;
            cp[tj] = same ? fmaxf(cp[tj], v) : cp[tj];
          }
          posmx[si] = pm;
          negsm[si] = ns;
        }

      // column-stat reduce: quads via shuffle, wm halves via idle buf1 scratch
#pragma unroll
      for (int tj = 0; tj < 4; ++tj) {
        cp[tj] = fmaxf(cp[tj], __shfl_xor(cp[tj], 16));
        cp[tj] = fmaxf(cp[tj], __shfl_xor(cp[tj], 32));
        cn[tj] += __shfl_xor(cn[tj], 16);
        cn[tj] += __shfl_xor(cn[tj], 32);
      }
      float* sred = (float*)&Bs[1][0];   // buf1: dead until next tile's phase A
      if (wm == 1 && quad == 0) {
#pragma unroll
        for (int tj = 0; tj < 4; ++tj) {
          sred[wn * 64 + tj * 16 + l16] = cp[tj];
          sred[128 + wn * 64 + tj * 16 + l16] = cn[tj];
        }
      }
      __syncthreads();           // scratch visible
      if (wm == 0 && quad == 0) {
#pragma unroll
        for (int tj = 0; tj < 4; ++tj) {
          const int C = colBase + wn * 64 + tj * 16 + l16;   // coalesced over l16
          posPart[(size_t)(8 + d) * BN + C] = fmaxf(cp[tj], sred[wn * 64 + tj * 16 + l16]);
          negPart[(size_t)(8 + d) * BN + C] = cn[tj] + sred[128 + wn * 64 + tj * 16 + l16];
        }
      }
      __syncthreads();           // sred reads done before next tile stages buf1
    }
  }
#undef STAGEB
#undef COMPUTE

  // ---- row stats: reduce across the 16 lanes sharing each row (cols split) ----
#pragma unroll
  for (int si = 0; si < 16; ++si) {
    float pm = posmx[si], ns = negsm[si];
#pragma unroll
    for (int m = 1; m < 16; m <<= 1) {
      pm = fmaxf(pm, __shfl_xor(pm, m));
      ns += __shfl_xor(ns, m);
    }
    posmx[si] = pm;
    negsm[si] = ns;
  }

  // ---- combine the wn=0 / wn=1 wave halves via LDS (reuse As) ----
  float* red = (float*)As;  // [0..127]=pos, [128..255]=neg
  __syncthreads();
  if (wn == 1 && l16 == 0) {
#pragma unroll
    for (int si = 0; si < 16; ++si) {
      const int rl = wm * 64 + (si >> 2) * 16 + quad * 4 + (si & 3);
      red[rl] = posmx[si];
      red[128 + rl] = negsm[si];
    }
  }
  __syncthreads();
  if (wn == 0 && l16 == 0) {
#pragma unroll
    for (int si = 0; si < 16; ++si) {
      const int rl = wm * 64 + (si >> 2) * 16 + quad * 4 + (si & 3);
      const float pm = fmaxf(posmx[si], red[rl]);
      const float ns = negsm[si] + red[128 + rl];
      posPart[(size_t)dg * BN + rowBase + rl] = pm;  // raw cosine max
      negPart[(size_t)dg * BN + rowBase + rl] = ns;
    }
  }
}

// ---------------- Kernel 3: per-row loss, accumulate, final division ----------------
// 32 blocks x 256: one thread per row; plane-major partials -> each of the NP
// reads is a fully-coalesced 256-thread load. Last block (atomic ticket)
// performs the division -- no separate epilogue kernel, no memset node.
__global__ void finalize_kernel(const float* __restrict__ posPart,
                                const float* __restrict__ negPart,
                                float* __restrict__ accum,
                                float* __restrict__ out) {
  const int tid = threadIdx.x;
  const int row = blockIdx.x * 256 + tid;
  float pm = -1e30f, ns = 0.0f;
#pragma unroll
  for (int g = 0; g < NP; ++g) {
    pm = fmaxf(pm, posPart[(size_t)g * BN + row]);
    ns += negPart[(size_t)g * BN + row];
  }
  float loss = 0.0f, c = 0.0f;
  if (pm > -1e29f && ns > 0.0f) {   // valid: has positive AND negative
    const float pos = pm * INV_T;
    const float lse = INV_T + logf(expf(pos - INV_T) + ns);
    loss = lse - pos;
    c = 1.0f;
  }
#pragma unroll
  for (int m = 1; m < 64; m <<= 1) {
    loss += __shfl_xor(loss, m);
    c += __shfl_xor(c, m);
  }
  __shared__ float sL[4], sC[4];
  const int wv = tid >> 6, lane = tid & 63;
  if (lane == 0) { sL[wv] = loss; sC[wv] = c; }
  __syncthreads();
  if (tid == 0) {
    atomicAdd(&accum[0], sL[0] + sL[1] + sL[2] + sL[3]);
    atomicAdd(&accum[1], sC[0] + sC[1] + sC[2] + sC[3]);
    __threadfence();
    const unsigned old = atomicAdd((unsigned*)&accum[2], 1u);
    if (old == 31u) {            // last block: totals are visible (fence+ticket)
      const float L = atomicAdd(&accum[0], 0.0f);
      const float C = atomicAdd(&accum[1], 0.0f);
      out[0] = (C > 0.0f) ? L / C : 0.0f;
    }
  }
}

extern "C" void kernel_launch(void* const* d_in, const int* in_sizes, int n_in,
                              void* d_out, int out_size, void* d_ws, size_t ws_size,
                              hipStream_t stream) {
  const float* E = (const float*)d_in[0];
  const int* cat = (const int*)d_in[1];
  // d_in[2] (font_labels) unused by the reference.

  // Workspace: [0,4MB) bf16 normalized embeddings; [NP][BN] partials x2; 12B accum.
  unsigned short* Eb = (unsigned short*)d_ws;
  float* posPart = (float*)((char*)d_ws + (size_t)BN * DK * 2);
  float* negPart = posPart + (size_t)NP * BN;
  float* accum = negPart + (size_t)NP * BN;
  float* out = (float*)d_out;

  hipLaunchKernelGGL(norm_kernel, dim3(BN / 4), dim3(256), 0, stream,
                     E, Eb, posPart, negPart, accum);
  hipLaunchKernelGGL(contrast_kernel, dim3(BN / TM, 9), dim3(256), 0, stream,
                     Eb, cat, posPart, negPart);
  hipLaunchKernelGGL(finalize_kernel, dim3(BN / 256), dim3(256), 0, stream,
                     posPart, negPart, accum, out);
}

// Round 5
// 143.917 us; speedup vs baseline: 1.0590x; 1.0138x over previous
//
#include <hip/hip_runtime.h>
#include <hip/hip_bf16.h>
#include <math.h>

// Problem constants (fixed by reference setup_inputs)
#define BN 8192       // batch
#define DK 256        // embedding dim (= GEMM K)
#define TM 128        // row/col tile
#define BK 32         // K chunk per pipeline stage
#define NP 41         // partial planes: 9 row-slots (dgroup) + 32 col-slots (d=1..32)
#define INV_T 1.42857142857142857f   // 1/0.7
#define C2E   2.060992915555662f     // log2(e)/0.7  (for exp2-based exp)

using bf16x8 = __attribute__((ext_vector_type(8))) short;  // 8 bf16 = 4 VGPRs
using f32x4  = __attribute__((ext_vector_type(4))) float;

__device__ __forceinline__ void async_copy16(void* lds, const void* g) {
  __builtin_amdgcn_global_load_lds(
      (const __attribute__((address_space(1))) unsigned int*)g,
      (__attribute__((address_space(3))) unsigned int*)lds,
      16, 0, 0);
}

// ---------------- Kernel 1: L2-normalize rows, fp32 -> bf16 ----------------
// One wave per row: float4 loads, shuffle reduce, ushort4 stores. No LDS.
// Also initializes the partial planes (plane-major [NP][BN]) and zeroes the
// 3-word accumulator (loss, count, ticket) so no hipMemset node is needed.
__global__ void norm_kernel(const float* __restrict__ E, unsigned short* __restrict__ Eb,
                            float* __restrict__ posPart, float* __restrict__ negPart,
                            float* __restrict__ accum) {
  const int gid = blockIdx.x * 256 + threadIdx.x;   // 2048*256 = 524288 threads
  if (gid < NP * BN) {                               // 335872 < 524288
    posPart[gid] = -1e30f;
    negPart[gid] = 0.0f;
  }
  if (blockIdx.x == 0 && threadIdx.x < 3) accum[threadIdx.x] = 0.0f;  // bits 0 == uint 0
  const int wv = threadIdx.x >> 6, lane = threadIdx.x & 63;
  const int row = blockIdx.x * 4 + wv;
  const float4 x = *(const float4*)&E[(size_t)row * DK + lane * 4];
  float ss = x.x * x.x + x.y * x.y + x.z * x.z + x.w * x.w;
#pragma unroll
  for (int m = 1; m < 64; m <<= 1) ss += __shfl_xor(ss, m);
  const float scale = 1.0f / fmaxf(sqrtf(ss), 1e-12f);
  ushort4 o;
  __hip_bfloat16 h0 = __float2bfloat16(x.x * scale); o.x = *(unsigned short*)&h0;
  __hip_bfloat16 h1 = __float2bfloat16(x.y * scale); o.y = *(unsigned short*)&h1;
  __hip_bfloat16 h2 = __float2bfloat16(x.z * scale); o.z = *(unsigned short*)&h2;
  __hip_bfloat16 h3 = __float2bfloat16(x.w * scale); o.w = *(unsigned short*)&h3;
  *(ushort4*)&Eb[(size_t)row * DK + lane * 4] = o;
}

// ---------------- Kernel 2: fused sims + masked max / sum-exp ----------------
// SYMMETRIC-HALVED tile set (each unordered 128x128 block-pair once):
// (I, (I+d)&63) for d=0..31 all I, plus d=32 for I<32 -> 2080 tiles.
// Block = (I, dgroup): dg<8 -> d=4dg..4dg+3; dg==8 (I<32, mapped to
// blockIdx.y==0 so they dispatch first) -> d=32.
//
// MINIMAL-BODY PIPELINE: Bs is a BK=32 ping-pong pair addressed by a runtime
// byte-offset parity ((kc&1)*8192 -- address arithmetic, never a register
// array index). Inner body = ONE stage + ONE compute + ONE barrier, 7 iters,
// unroll 1: rounds 2/3/4 showed that any larger body (2-deep B-in-reg, full
// 8x unroll, 2-phase macro pair) tips the allocator into scratch spill
// (WRITE_SIZE 2.5 -> 16..43 MB); round 1's small body (116 VGPR) did not.
// Stage(kc+1) issues BEFORE compute(kc), so the barrier's vmcnt(0) drain is
// hidden under ~a full compute phase. One exposed stage per tile start only.
// CONFLICT-FREE LDS (r3/r4-proven, SQ_LDS_BANK_CONFLICT = 0): As and Bs hold
// [panel][kq][c16] 16B chunks so each ds_read_b128 reads 1024 CONTIGUOUS
// bytes; staging keeps full 64B-sector efficiency.
// LDS = 64 KB As + 16 KB Bs = 80 KB -> 2 blocks/CU.
// Partials: plane-major [NP][BN]; plane = dg (row stats) or 8+d (col stats).
__launch_bounds__(256, 2)
__global__ void contrast_kernel(const unsigned short* __restrict__ Eb,
                                const int* __restrict__ cat,
                                float* __restrict__ posPart,
                                float* __restrict__ negPart) {
  // As chunk layout: idx = (rh*8 + kc)*64 + q*16 + c16
  //   holds global A[row = rh*16 + c16][k = kc*32 + q*8 .. +8]
  __shared__ __align__(16) unsigned short As[TM * DK];       // 64 KB
  // Bs chunk layout (per 8 KB buffer): idx = colhi*64 + q*16 + c16
  //   holds global B[col = colhi*16 + c16][k = kc*32 + q*8 .. +8]
  __shared__ __align__(16) unsigned short Bs[2 * TM * BK];   // 16 KB ping-pong

  const int tid = threadIdx.x;
  const int lane = tid & 63;
  const int wv = tid >> 6;
  const int wm = wv >> 1;      // wave row (0..1)
  const int wn = wv & 1;       // wave col (0..1)
  const int quad = lane >> 4;
  const int l16 = lane & 15;

  const int I = blockIdx.x;
  const int dg = (blockIdx.y == 0) ? 8 : (int)blockIdx.y - 1;  // light blocks first
  if (dg == 8 && I >= 32) return;      // d=32 tiles exist only for I<32
  const int ntiles = (dg == 8) ? 1 : 4;
  const int rowBase = I * TM;

// Stage one BK=32 B chunk (8 KB, 2 copies/thread) for columns [cb, cb+128)
// into Bs at byte offset ldsoff (0 or 8192).
#define STAGEB(ldsoff, cb, kcs)                                               \
  {                                                                           \
    _Pragma("unroll") for (int r2 = 0; r2 < 2; ++r2) {                        \
      const int idx = tid + r2 * 256;                                         \
      const int colhi = idx >> 6, q = (idx >> 4) & 3, c16 = idx & 15;         \
      async_copy16((char*)Bs + (ldsoff) + idx * 16,                           \
                   (const char*)Eb + (size_t)((cb) + colhi * 16 + c16) * 512  \
                       + (kcs) * 64 + q * 16);                                \
    }                                                                         \
  }

// One K=32 step: 4 A frags + 4 B frags (contiguous 1024B ds_read_b128 each),
// 16 MFMA with raised priority.
#define COMPUTE(ldsoff, kcc)                                                  \
  {                                                                           \
    bf16x8 a[4], b[4];                                                        \
    _Pragma("unroll") for (int ti = 0; ti < 4; ++ti)                          \
      a[ti] = *(const bf16x8*)((const char*)As +                              \
              ((((wm * 4 + ti) * 8 + (kcc)) * 64 + quad * 16 + l16) * 16));   \
    _Pragma("unroll") for (int tj = 0; tj < 4; ++tj)                          \
      b[tj] = *(const bf16x8*)((const char*)Bs + (ldsoff) +                   \
              (((wn * 4 + tj) * 64 + quad * 16 + l16) * 16));                 \
    __builtin_amdgcn_s_setprio(1);                                            \
    _Pragma("unroll") for (int ti = 0; ti < 4; ++ti)                          \
      _Pragma("unroll") for (int tj = 0; tj < 4; ++tj)                        \
        acc[ti][tj] = __builtin_amdgcn_mfma_f32_16x16x32_bf16(                \
            a[ti], b[tj], acc[ti][tj], 0, 0, 0);                              \
    __builtin_amdgcn_s_setprio(0);                                            \
  }

  // ---- prologue: stage full A panel (drained by the first tile's barrier) ----
  {
    const char* gbase = (const char*)(Eb + (size_t)rowBase * DK);
#pragma unroll
    for (int i = 0; i < 16; ++i) {
      const int idx = tid + i * 256;       // 4096 chunks of 16B
      const int rhkc = idx >> 6;           // rh = rhkc>>3, kc = rhkc&7
      const int q = (idx >> 4) & 3, c16 = idx & 15;
      async_copy16((char*)As + idx * 16,
                   gbase + ((rhkc >> 3) * 16 + c16) * 512 +
                       ((rhkc & 7) * 4 + q) * 16);
    }
  }

  // Rows owned by this lane (C layout: col=lane&15, row=quad*4+reg):
  int catRow[16];
  float posmx[16], negsm[16];
#pragma unroll
  for (int ti = 0; ti < 4; ++ti)
#pragma unroll
    for (int r = 0; r < 4; ++r) {
      const int si = ti * 4 + r;
      catRow[si] = cat[rowBase + wm * 64 + ti * 16 + quad * 4 + r];
      posmx[si] = -1e30f;
      negsm[si] = 0.0f;
    }

#pragma unroll 1
  for (int t = 0; t < ntiles; ++t) {
    const int d = (dg == 8) ? 32 : dg * 4 + t;   // block-distance of this tile
    const int colBase = ((I + d) & 63) * TM;

    // tile-start: stage chunk 0 into buf0 (exposed once per tile; for t=0
    // this barrier also drains the A-panel loads)
    STAGEB(0, colBase, 0);
    __syncthreads();

    f32x4 acc[4][4];
#pragma unroll
    for (int ti = 0; ti < 4; ++ti)
#pragma unroll
      for (int tj = 0; tj < 4; ++tj)
        acc[ti][tj] = f32x4{0.f, 0.f, 0.f, 0.f};

    // pipeline: stage(kc+1 -> other buf) || compute(kc); one barrier per kc.
#pragma unroll 1
    for (int kc = 0; kc < 7; ++kc) {
      STAGEB(((kc + 1) & 1) * 8192, colBase, kc + 1);
      COMPUTE((kc & 1) * 8192, kc);
      __syncthreads();   // stage landed (hidden under compute)
    }
    COMPUTE(8192, 7);    // buf1, staged at kc=6; buf0 is now dead -> scratch

    // ---- fused epilogue for this 128x128 tile (acc = raw cosines) ----
    int catCol[4];
#pragma unroll
    for (int tj = 0; tj < 4; ++tj) catCol[tj] = cat[colBase + wn * 64 + tj * 16 + l16];

    if (d == 0) {
      // diagonal tile: row stats only; self-exclusion needed; no col stats
#pragma unroll
      for (int ti = 0; ti < 4; ++ti)
#pragma unroll
        for (int r = 0; r < 4; ++r) {
          const int si = ti * 4 + r;
          const int rl = wm * 64 + ti * 16 + quad * 4 + r;   // local row
          float pm = posmx[si];
          float ns = negsm[si];
#pragma unroll
          for (int tj = 0; tj < 4; ++tj) {
            const float v = acc[ti][tj][r];
            const bool same = (catRow[si] == catCol[tj]);
            const bool self = (rl == wn * 64 + tj * 16 + l16);
            const float e = exp2f(__fmaf_rn(v, C2E, -C2E));
            ns += same ? 0.0f : e;
            pm = (same && !self) ? fmaxf(pm, v) : pm;
          }
          posmx[si] = pm;
          negsm[si] = ns;
        }
    } else {
      // off-diagonal: row stats + column stats (no self possible, I != J)
      float cp[4], cn[4];
#pragma unroll
      for (int tj = 0; tj < 4; ++tj) { cp[tj] = -1e30f; cn[tj] = 0.0f; }
#pragma unroll
      for (int ti = 0; ti < 4; ++ti)
#pragma unroll
        for (int r = 0; r < 4; ++r) {
          const int si = ti * 4 + r;
          float pm = posmx[si];
          float ns = negsm[si];
#pragma unroll
          for (int tj = 0; tj < 4; ++tj) {
            const float v = acc[ti][tj][r];
            const bool same = (catRow[si] == catCol[tj]);
            const float e = exp2f(__fmaf_rn(v, C2E, -C2E));
            const float en = same ? 0.0f : e;
            ns += en;
            cn[tj] += en;
            pm = same ? fmaxf(pm, v) : pm;
            cp[tj] = same ? fmaxf(cp[tj], v) : cp[tj];
          }
          posmx[si] = pm;
          negsm[si] = ns;
        }

      // column-stat reduce: quads via shuffle, wm halves via buf0 scratch
      // (buf0's last reader was COMPUTE(kc=6), barrier-protected; other
      // waves may still read buf1 in COMPUTE(7) -- disjoint region)
#pragma unroll
      for (int tj = 0; tj < 4; ++tj) {
        cp[tj] = fmaxf(cp[tj], __shfl_xor(cp[tj], 16));
        cp[tj] = fmaxf(cp[tj], __shfl_xor(cp[tj], 32));
        cn[tj] += __shfl_xor(cn[tj], 16);
        cn[tj] += __shfl_xor(cn[tj], 32);
      }
      float* sred = (float*)Bs;   // buf0
      if (wm == 1 && quad == 0) {
#pragma unroll
        for (int tj = 0; tj < 4; ++tj) {
          sred[wn * 64 + tj * 16 + l16] = cp[tj];
          sred[128 + wn * 64 + tj * 16 + l16] = cn[tj];
        }
      }
      __syncthreads();           // scratch visible
      if (wm == 0 && quad == 0) {
#pragma unroll
        for (int tj = 0; tj < 4; ++tj) {
          const int C = colBase + wn * 64 + tj * 16 + l16;   // coalesced over l16
          posPart[(size_t)(8 + d) * BN + C] = fmaxf(cp[tj], sred[wn * 64 + tj * 16 + l16]);
          negPart[(size_t)(8 + d) * BN + C] = cn[tj] + sred[128 + wn * 64 + tj * 16 + l16];
        }
      }
      __syncthreads();           // sred reads done before next tile stages buf0
    }
  }
#undef STAGEB
#undef COMPUTE

  // ---- row stats: reduce across the 16 lanes sharing each row (cols split) ----
#pragma unroll
  for (int si = 0; si < 16; ++si) {
    float pm = posmx[si], ns = negsm[si];
#pragma unroll
    for (int m = 1; m < 16; m <<= 1) {
      pm = fmaxf(pm, __shfl_xor(pm, m));
      ns += __shfl_xor(ns, m);
    }
    posmx[si] = pm;
    negsm[si] = ns;
  }

  // ---- combine the wn=0 / wn=1 wave halves via LDS (reuse As) ----
  float* red = (float*)As;  // [0..127]=pos, [128..255]=neg
  __syncthreads();
  if (wn == 1 && l16 == 0) {
#pragma unroll
    for (int si = 0; si < 16; ++si) {
      const int rl = wm * 64 + (si >> 2) * 16 + quad * 4 + (si & 3);
      red[rl] = posmx[si];
      red[128 + rl] = negsm[si];
    }
  }
  __syncthreads();
  if (wn == 0 && l16 == 0) {
#pragma unroll
    for (int si = 0; si < 16; ++si) {
      const int rl = wm * 64 + (si >> 2) * 16 + quad * 4 + (si & 3);
      const float pm = fmaxf(posmx[si], red[rl]);
      const float ns = negsm[si] + red[128 + rl];
      posPart[(size_t)dg * BN + rowBase + rl] = pm;  // raw cosine max
      negPart[(size_t)dg * BN + rowBase + rl] = ns;
    }
  }
}

// ---------------- Kernel 3: per-row loss, accumulate, final division ----------------
// 32 blocks x 256: one thread per row; plane-major partials -> each of the NP
// reads is a fully-coalesced 256-thread load. Last block (atomic ticket)
// performs the division -- no separate epilogue kernel, no memset node.
__global__ void finalize_kernel(const float* __restrict__ posPart,
                                const float* __restrict__ negPart,
                                float* __restrict__ accum,
                                float* __restrict__ out) {
  const int tid = threadIdx.x;
  const int row = blockIdx.x * 256 + tid;
  float pm = -1e30f, ns = 0.0f;
#pragma unroll
  for (int g = 0; g < NP; ++g) {
    pm = fmaxf(pm, posPart[(size_t)g * BN + row]);
    ns += negPart[(size_t)g * BN + row];
  }
  float loss = 0.0f, c = 0.0f;
  if (pm > -1e29f && ns > 0.0f) {   // valid: has positive AND negative
    const float pos = pm * INV_T;
    const float lse = INV_T + logf(expf(pos - INV_T) + ns);
    loss = lse - pos;
    c = 1.0f;
  }
#pragma unroll
  for (int m = 1; m < 64; m <<= 1) {
    loss += __shfl_xor(loss, m);
    c += __shfl_xor(c, m);
  }
  __shared__ float sL[4], sC[4];
  const int wv = tid >> 6, lane = tid & 63;
  if (lane == 0) { sL[wv] = loss; sC[wv] = c; }
  __syncthreads();
  if (tid == 0) {
    atomicAdd(&accum[0], sL[0] + sL[1] + sL[2] + sL[3]);
    atomicAdd(&accum[1], sC[0] + sC[1] + sC[2] + sC[3]);
    __threadfence();
    const unsigned old = atomicAdd((unsigned*)&accum[2], 1u);
    if (old == 31u) {            // last block: totals are visible (fence+ticket)
      const float L = atomicAdd(&accum[0], 0.0f);
      const float C = atomicAdd(&accum[1], 0.0f);
      out[0] = (C > 0.0f) ? L / C : 0.0f;
    }
  }
}

extern "C" void kernel_launch(void* const* d_in, const int* in_sizes, int n_in,
                              void* d_out, int out_size, void* d_ws, size_t ws_size,
                              hipStream_t stream) {
  const float* E = (const float*)d_in[0];
  const int* cat = (const int*)d_in[1];
  // d_in[2] (font_labels) unused by the reference.

  // Workspace: [0,4MB) bf16 normalized embeddings; [NP][BN] partials x2; 12B accum.
  unsigned short* Eb = (unsigned short*)d_ws;
  float* posPart = (float*)((char*)d_ws + (size_t)BN * DK * 2);
  float* negPart = posPart + (size_t)NP * BN;
  float* accum = negPart + (size_t)NP * BN;
  float* out = (float*)d_out;

  hipLaunchKernelGGL(norm_kernel, dim3(BN / 4), dim3(256), 0, stream,
                     E, Eb, posPart, negPart, accum);
  hipLaunchKernelGGL(contrast_kernel, dim3(BN / TM, 9), dim3(256), 0, stream,
                     Eb, cat, posPart, negPart);
  hipLaunchKernelGGL(finalize_kernel, dim3(BN / 256), dim3(256), 0, stream,
                     posPart, negPart, accum, out);
}